// Round 3
// baseline (66.728 us; speedup 1.0000x reference)
//
#include <hip/hip_runtime.h>
#include <math.h>

#define N_SRC 12000
#define N_TAR 12000
#define NT_CHUNKS 80
#define CHUNK 150            // N_TAR / NT_CHUNKS (exact)
#define SRC_PER_BLOCK 1024   // 256 threads * 4 src each
#define SRC_BLOCKS 12        // ceil(N_SRC / 1024) -> 12*1024 = 12288 (ragged ok)
#define MAH_BLOCKS 47        // ceil(N_SRC / 256)

// ---------------------------------------------------------------------------
// Kernel 1: brute-force NN partial argmin. No LDS: the target stream is
// wave-uniform, so targets are read straight from global (compiler emits
// s_load into SGPRs for uniform __restrict__ reads; worst case a vector
// load from L2 — either way the per-CU LDS pipe is out of the picture).
// score(i,j) = |tar_j(3d)|^2 - 2*dot3(tsrc_i, tar_j)  (row-constant terms
// dropped; argmin-equivalent to reference since tar.w == 1 exactly).
// 4 sources/thread: per-j VALU (27 instr) dominates load issue.
// ---------------------------------------------------------------------------
__global__ __launch_bounds__(256) void nn_partial_kernel(
    const float* __restrict__ T,
    const float* __restrict__ src,
    const float* __restrict__ tar,
    float* __restrict__ pval,
    int*   __restrict__ pidx)
{
    const int tid   = threadIdx.x;
    const int sblk  = blockIdx.x;
    const int chunk = blockIdx.y;
    const int jbase = chunk * CHUNK;

    // rows of T (tsrc = T @ p)
    const float T00=T[0],  T01=T[1],  T02=T[2],  T03=T[3];
    const float T10=T[4],  T11=T[5],  T12=T[6],  T13=T[7];
    const float T20=T[8],  T21=T[9],  T22=T[10], T23=T[11];

    float sx[4], sy[4], sz[4], mval[4];
    int   mi[4], si[4];
    #pragma unroll
    for (int k = 0; k < 4; ++k) {
        int i = sblk * SRC_PER_BLOCK + k * 256 + tid;
        si[k] = i;
        float px = 0.f, py = 0.f, pz = 0.f, pw = 1.f;
        if (i < N_SRC) {
            float4 p = ((const float4*)src)[i];
            px = p.x; py = p.y; pz = p.z; pw = p.w;
        }
        float tx = T00*px + T01*py + T02*pz + T03*pw;
        float ty = T10*px + T11*py + T12*pz + T13*pw;
        float tz = T20*px + T21*py + T22*pz + T23*pw;
        sx[k] = -2.0f * tx;
        sy[k] = -2.0f * ty;
        sz[k] = -2.0f * tz;
        mval[k] = INFINITY;
        mi[k]   = 0;
    }

    const float4* tar4 = (const float4*)tar;
    #pragma unroll 6
    for (int j = 0; j < CHUNK; ++j) {
        const float4 t = tar4[jbase + j];          // wave-uniform address
        const float n3 = fmaf(t.x, t.x, fmaf(t.y, t.y, t.z * t.z));
        const int idx = jbase + j;
        #pragma unroll
        for (int k = 0; k < 4; ++k) {
            float s = fmaf(sx[k], t.x, fmaf(sy[k], t.y, fmaf(sz[k], t.z, n3)));
            if (s < mval[k]) { mval[k] = s; mi[k] = idx; }
        }
    }

    #pragma unroll
    for (int k = 0; k < 4; ++k) {
        if (si[k] < N_SRC) {
            pval[chunk * N_SRC + si[k]] = mval[k];
            pidx[chunk * N_SRC + si[k]] = mi[k];
        }
    }
}

// ---------------------------------------------------------------------------
// Kernel 2: combine chunk partials (ascending chunk order + strict < gives
// the reference's first-min tie-break), then covariance congruence, 3x3
// adjugate inverse, Mahalanobis form; block reduce -> per-block partial sum
// (no atomics, no zero-init needed: every block writes its slot).
// ---------------------------------------------------------------------------
__global__ __launch_bounds__(256) void mah_kernel(
    const float* __restrict__ T,
    const float* __restrict__ src,
    const float* __restrict__ tar,
    const float* __restrict__ cs,   // covs_src  [N][16]
    const float* __restrict__ ct,   // covs_tar  [N][16]
    const float* __restrict__ pval,
    const int*   __restrict__ pidx,
    float* __restrict__ bsum)
{
    const int i = blockIdx.x * 256 + threadIdx.x;
    float mah = 0.0f;

    if (i < N_SRC) {
        float best = INFINITY; int bidx = 0;
        #pragma unroll 8
        for (int c = 0; c < NT_CHUNKS; ++c) {
            float v  = pval[c * N_SRC + i];
            int   ix = pidx[c * N_SRC + i];
            if (v < best) { best = v; bidx = ix; }
        }

        float Tm[4][4];
        #pragma unroll
        for (int a = 0; a < 16; ++a) ((float*)Tm)[a] = T[a];

        float C[4][4];
        #pragma unroll
        for (int a = 0; a < 16; ++a) ((float*)C)[a] = cs[i * 16 + a];

        // B[j][c] = sum_k C[j][k] * T[c][k]   (c = 0..2)
        float B[4][3];
        #pragma unroll
        for (int j = 0; j < 4; ++j)
            #pragma unroll
            for (int c = 0; c < 3; ++c)
                B[j][c] = C[j][0]*Tm[c][0] + C[j][1]*Tm[c][1]
                        + C[j][2]*Tm[c][2] + C[j][3]*Tm[c][3];

        // M[r][c] = sum_j T[r][j] * B[j][c] + covs_tar[bidx][r][c]
        const float* ctb = ct + (size_t)bidx * 16;
        float M[3][3];
        #pragma unroll
        for (int r = 0; r < 3; ++r)
            #pragma unroll
            for (int c = 0; c < 3; ++c)
                M[r][c] = Tm[r][0]*B[0][c] + Tm[r][1]*B[1][c]
                        + Tm[r][2]*B[2][c] + Tm[r][3]*B[3][c]
                        + ctb[r * 4 + c];

        const float a_ = M[0][0], b_ = M[0][1], c_ = M[0][2];
        const float d_ = M[1][0], e_ = M[1][1], f_ = M[1][2];
        const float g_ = M[2][0], h_ = M[2][1], i_ = M[2][2];

        const float A0 = e_*i_ - f_*h_;
        const float A1 = f_*g_ - d_*i_;
        const float A2 = d_*h_ - e_*g_;
        const float det = a_*A0 + b_*A1 + c_*A2;
        const float rdet = 1.0f / det;

        float inv[3][3];
        inv[0][0] = A0 * rdet;
        inv[0][1] = (c_*h_ - b_*i_) * rdet;
        inv[0][2] = (b_*f_ - c_*e_) * rdet;
        inv[1][0] = A1 * rdet;
        inv[1][1] = (a_*i_ - c_*g_) * rdet;
        inv[1][2] = (c_*d_ - a_*f_) * rdet;
        inv[2][0] = A2 * rdet;
        inv[2][1] = (b_*g_ - a_*h_) * rdet;
        inv[2][2] = (a_*e_ - b_*d_) * rdet;

        // loss branch: pT = src @ T  (columns of T)
        float4 p = ((const float4*)src)[i];
        float p0 = p.x*Tm[0][0] + p.y*Tm[1][0] + p.z*Tm[2][0] + p.w*Tm[3][0];
        float p1 = p.x*Tm[0][1] + p.y*Tm[1][1] + p.z*Tm[2][1] + p.w*Tm[3][1];
        float p2 = p.x*Tm[0][2] + p.y*Tm[1][2] + p.z*Tm[2][2] + p.w*Tm[3][2];

        const float4 tp = ((const float4*)tar)[bidx];
        const float r0 = tp.x - p0;
        const float r1 = tp.y - p1;
        const float r2 = tp.z - p2;

        mah = r0*(inv[0][0]*r0 + inv[0][1]*r1 + inv[0][2]*r2)
            + r1*(inv[1][0]*r0 + inv[1][1]*r1 + inv[1][2]*r2)
            + r2*(inv[2][0]*r0 + inv[2][1]*r1 + inv[2][2]*r2);
    }

    // block reduction: wave shuffle + LDS across 4 waves (deterministic)
    float v = mah;
    #pragma unroll
    for (int off = 32; off > 0; off >>= 1)
        v += __shfl_down(v, off, 64);

    __shared__ float wsum[4];
    if ((threadIdx.x & 63) == 0) wsum[threadIdx.x >> 6] = v;
    __syncthreads();
    if (threadIdx.x == 0)
        bsum[blockIdx.x] = wsum[0] + wsum[1] + wsum[2] + wsum[3];
}

// ---------------------------------------------------------------------------
// Kernel 3: reduce the 47 block partials in double, write the mean.
// ---------------------------------------------------------------------------
__global__ __launch_bounds__(64) void finalize_kernel(
    const float* __restrict__ bsum,
    float* __restrict__ out)
{
    const int tid = threadIdx.x;
    double v = (tid < MAH_BLOCKS) ? (double)bsum[tid] : 0.0;
    #pragma unroll
    for (int off = 32; off > 0; off >>= 1)
        v += __shfl_down(v, off, 64);
    if (tid == 0)
        out[0] = (float)(v / (double)N_SRC);
}

extern "C" void kernel_launch(void* const* d_in, const int* in_sizes, int n_in,
                              void* d_out, int out_size, void* d_ws, size_t ws_size,
                              hipStream_t stream) {
    const float* T   = (const float*)d_in[0];
    const float* src = (const float*)d_in[1];
    const float* tar = (const float*)d_in[2];
    const float* cs  = (const float*)d_in[3];
    const float* ct  = (const float*)d_in[4];
    float* out = (float*)d_out;

    char* ws = (char*)d_ws;
    float* pval = (float*)ws;                                      // 80*12000*4
    int*   pidx = (int*)(ws + (size_t)NT_CHUNKS * N_SRC * 4);      // 80*12000*4
    float* bsum = (float*)(ws + (size_t)NT_CHUNKS * N_SRC * 8);    // 47 floats

    dim3 g1(SRC_BLOCKS, NT_CHUNKS);
    nn_partial_kernel<<<g1, 256, 0, stream>>>(T, src, tar, pval, pidx);

    mah_kernel<<<MAH_BLOCKS, 256, 0, stream>>>(
        T, src, tar, cs, ct, pval, pidx, bsum);

    finalize_kernel<<<1, 64, 0, stream>>>(bsum, out);
}

// Round 4
// 41.450 us; speedup vs baseline: 1.6098x; 1.6098x over previous
//
#include <hip/hip_runtime.h>
#include <math.h>

#define N_PTS 12000
#define NT_CHUNKS 150
#define CHUNK 80             // N_TAR / NT_CHUNKS (exact)
#define SRC_PER_BLOCK 2048   // 256 threads * 8 src each
#define SRC_BLOCKS 6         // 6*2048 = 12288 >= 12000 (ragged last block)
#define MAH_BLOCKS 47        // ceil(12000/256)

// ---------------------------------------------------------------------------
// Kernel 1: brute-force NN partial min (VALUE ONLY — no index bookkeeping).
// score(i,j) = |tar_j3|^2 - 2*dot3(tsrc_i, tar_j): argmin-equivalent to the
// reference d2 (row-constant terms dropped; tar.w == 1 exactly).
// Per pair: 3 FMA + 1 v_min_f32. Targets staged in LDS as [x,y,z,|t|^2];
// per-j reads are wave-uniform broadcasts (conflict-free).
// All score arithmetic is explicit fmaf so kernel 2 can recompute the exact
// same bits when recovering the argmin index.
// Block (0,0) also resets the completion counter used by kernel 2's fused
// finalize (safe: kernel 2 only starts after this kernel fully completes).
// ---------------------------------------------------------------------------
__global__ __launch_bounds__(256) void nn_partial_kernel(
    const float* __restrict__ T,
    const float* __restrict__ src,
    const float* __restrict__ tar,
    float* __restrict__ pval,
    unsigned int* __restrict__ counter)
{
    __shared__ float4 lds[CHUNK];
    const int tid   = threadIdx.x;
    const int sblk  = blockIdx.x;
    const int chunk = blockIdx.y;
    const int jbase = chunk * CHUNK;

    if (sblk == 0 && chunk == 0 && tid == 0) atomicExch(counter, 0u);

    // rows of T (tsrc = T @ p)
    const float T00=T[0],  T01=T[1],  T02=T[2],  T03=T[3];
    const float T10=T[4],  T11=T[5],  T12=T[6],  T13=T[7];
    const float T20=T[8],  T21=T[9],  T22=T[10], T23=T[11];

    if (tid < CHUNK) {
        float4 t = ((const float4*)tar)[jbase + tid];
        float n3 = fmaf(t.x, t.x, fmaf(t.y, t.y, t.z * t.z));
        lds[tid] = make_float4(t.x, t.y, t.z, n3);
    }
    __syncthreads();

    float sx[8], sy[8], sz[8], mval[8];
    const int base = sblk * SRC_PER_BLOCK + tid;
    #pragma unroll
    for (int k = 0; k < 8; ++k) {
        int i = base + k * 256;
        if (i >= N_PTS) i = N_PTS - 1;          // clamp (write is guarded)
        float4 p = ((const float4*)src)[i];
        float tx = fmaf(T00, p.x, fmaf(T01, p.y, fmaf(T02, p.z, T03 * p.w)));
        float ty = fmaf(T10, p.x, fmaf(T11, p.y, fmaf(T12, p.z, T13 * p.w)));
        float tz = fmaf(T20, p.x, fmaf(T21, p.y, fmaf(T22, p.z, T23 * p.w)));
        sx[k] = -2.0f * tx;
        sy[k] = -2.0f * ty;
        sz[k] = -2.0f * tz;
        mval[k] = INFINITY;
    }

    #pragma unroll 4
    for (int j = 0; j < CHUNK; ++j) {
        const float4 t = lds[j];
        #pragma unroll
        for (int k = 0; k < 8; ++k) {
            float s = fmaf(sx[k], t.x, fmaf(sy[k], t.y, fmaf(sz[k], t.z, t.w)));
            mval[k] = fminf(mval[k], s);
        }
    }

    #pragma unroll
    for (int k = 0; k < 8; ++k) {
        int i = base + k * 256;
        if (i < N_PTS) pval[chunk * N_PTS + i] = mval[k];
    }
}

// ---------------------------------------------------------------------------
// Kernel 2: per source — pick winning chunk (strict < over ascending chunks
// = first chunk at global min), rescan that chunk with bit-identical fmaf
// math to recover the first argmin index; then covariance congruence, 3x3
// adjugate inverse, Mahalanobis; block reduce; last finished block does the
// deterministic fixed-order final reduce (device-scope atomics + fences).
// ---------------------------------------------------------------------------
__global__ __launch_bounds__(256) void mah_finalize_kernel(
    const float* __restrict__ T,
    const float* __restrict__ src,
    const float* __restrict__ tar,
    const float* __restrict__ cs,   // covs_src  [N][16]
    const float* __restrict__ ct,   // covs_tar  [N][16]
    const float* __restrict__ pval,
    float* __restrict__ bsum,
    unsigned int* __restrict__ counter,
    float* __restrict__ out)
{
    const int i = blockIdx.x * 256 + threadIdx.x;
    float mah = 0.0f;

    if (i < N_PTS) {
        float Tm[4][4];
        #pragma unroll
        for (int a = 0; a < 16; ++a) ((float*)Tm)[a] = T[a];

        // --- chunk combine: first chunk achieving the global min ---
        float best = INFINITY; int bc = 0;
        #pragma unroll 10
        for (int c = 0; c < NT_CHUNKS; ++c) {
            float v = pval[c * N_PTS + i];
            if (v < best) { best = v; bc = c; }
        }

        // --- rescan winning chunk: recompute scores bit-identically ---
        float4 p = ((const float4*)src)[i];
        float tx = fmaf(Tm[0][0], p.x, fmaf(Tm[0][1], p.y, fmaf(Tm[0][2], p.z, Tm[0][3] * p.w)));
        float ty = fmaf(Tm[1][0], p.x, fmaf(Tm[1][1], p.y, fmaf(Tm[1][2], p.z, Tm[1][3] * p.w)));
        float tz = fmaf(Tm[2][0], p.x, fmaf(Tm[2][1], p.y, fmaf(Tm[2][2], p.z, Tm[2][3] * p.w)));
        const float sx = -2.0f * tx, sy = -2.0f * ty, sz = -2.0f * tz;

        const int jbase = bc * CHUNK;
        float best2 = INFINITY; int bidx = 0;
        #pragma unroll 8
        for (int j = 0; j < CHUNK; ++j) {
            float4 t = ((const float4*)tar)[jbase + j];
            float n3 = fmaf(t.x, t.x, fmaf(t.y, t.y, t.z * t.z));
            float s = fmaf(sx, t.x, fmaf(sy, t.y, fmaf(sz, t.z, n3)));
            if (s < best2) { best2 = s; bidx = jbase + j; }
        }

        // --- covariance congruence + combined 3x3 ---
        float C[4][4];
        #pragma unroll
        for (int a = 0; a < 16; ++a) ((float*)C)[a] = cs[i * 16 + a];

        float B[4][3];
        #pragma unroll
        for (int j = 0; j < 4; ++j)
            #pragma unroll
            for (int c = 0; c < 3; ++c)
                B[j][c] = C[j][0]*Tm[c][0] + C[j][1]*Tm[c][1]
                        + C[j][2]*Tm[c][2] + C[j][3]*Tm[c][3];

        const float* ctb = ct + (size_t)bidx * 16;
        float M[3][3];
        #pragma unroll
        for (int r = 0; r < 3; ++r)
            #pragma unroll
            for (int c = 0; c < 3; ++c)
                M[r][c] = Tm[r][0]*B[0][c] + Tm[r][1]*B[1][c]
                        + Tm[r][2]*B[2][c] + Tm[r][3]*B[3][c]
                        + ctb[r * 4 + c];

        const float a_ = M[0][0], b_ = M[0][1], c_ = M[0][2];
        const float d_ = M[1][0], e_ = M[1][1], f_ = M[1][2];
        const float g_ = M[2][0], h_ = M[2][1], i_ = M[2][2];

        const float A0 = e_*i_ - f_*h_;
        const float A1 = f_*g_ - d_*i_;
        const float A2 = d_*h_ - e_*g_;
        const float det = a_*A0 + b_*A1 + c_*A2;
        const float rdet = 1.0f / det;

        float inv[3][3];
        inv[0][0] = A0 * rdet;
        inv[0][1] = (c_*h_ - b_*i_) * rdet;
        inv[0][2] = (b_*f_ - c_*e_) * rdet;
        inv[1][0] = A1 * rdet;
        inv[1][1] = (a_*i_ - c_*g_) * rdet;
        inv[1][2] = (c_*d_ - a_*f_) * rdet;
        inv[2][0] = A2 * rdet;
        inv[2][1] = (b_*g_ - a_*h_) * rdet;
        inv[2][2] = (a_*e_ - b_*d_) * rdet;

        // loss branch: pT = src @ T (columns of T)
        float p0 = p.x*Tm[0][0] + p.y*Tm[1][0] + p.z*Tm[2][0] + p.w*Tm[3][0];
        float p1 = p.x*Tm[0][1] + p.y*Tm[1][1] + p.z*Tm[2][1] + p.w*Tm[3][1];
        float p2 = p.x*Tm[0][2] + p.y*Tm[1][2] + p.z*Tm[2][2] + p.w*Tm[3][2];

        const float4 tp = ((const float4*)tar)[bidx];
        const float r0 = tp.x - p0;
        const float r1 = tp.y - p1;
        const float r2 = tp.z - p2;

        mah = r0*(inv[0][0]*r0 + inv[0][1]*r1 + inv[0][2]*r2)
            + r1*(inv[1][0]*r0 + inv[1][1]*r1 + inv[1][2]*r2)
            + r2*(inv[2][0]*r0 + inv[2][1]*r1 + inv[2][2]*r2);
    }

    // block reduction (deterministic)
    float v = mah;
    #pragma unroll
    for (int off = 32; off > 0; off >>= 1)
        v += __shfl_down(v, off, 64);

    __shared__ float wsum[4];
    __shared__ int lastflag;
    if ((threadIdx.x & 63) == 0) wsum[threadIdx.x >> 6] = v;
    __syncthreads();
    if (threadIdx.x == 0) {
        float tot = wsum[0] + wsum[1] + wsum[2] + wsum[3];
        atomicExch(&bsum[blockIdx.x], tot);       // device-scope visible write
        __threadfence();
        unsigned int old = atomicAdd(counter, 1u);
        lastflag = (old == MAH_BLOCKS - 1) ? 1 : 0;
    }
    __syncthreads();

    if (lastflag && threadIdx.x < 64) {
        __threadfence();                           // acquire
        double acc = 0.0;
        if (threadIdx.x < MAH_BLOCKS)
            acc = (double)atomicAdd(&bsum[threadIdx.x], 0.0f);  // coherent read
        #pragma unroll
        for (int off = 32; off > 0; off >>= 1)
            acc += __shfl_down(acc, off, 64);
        if (threadIdx.x == 0)
            out[0] = (float)(acc / (double)N_PTS);
    }
}

extern "C" void kernel_launch(void* const* d_in, const int* in_sizes, int n_in,
                              void* d_out, int out_size, void* d_ws, size_t ws_size,
                              hipStream_t stream) {
    const float* T   = (const float*)d_in[0];
    const float* src = (const float*)d_in[1];
    const float* tar = (const float*)d_in[2];
    const float* cs  = (const float*)d_in[3];
    const float* ct  = (const float*)d_in[4];
    float* out = (float*)d_out;

    char* ws = (char*)d_ws;
    unsigned int* counter = (unsigned int*)ws;             // 4 B
    float* bsum = (float*)(ws + 16);                       // 47 floats
    float* pval = (float*)(ws + 256);                      // 150*12000*4 = 7.2 MB

    dim3 g1(SRC_BLOCKS, NT_CHUNKS);
    nn_partial_kernel<<<g1, 256, 0, stream>>>(T, src, tar, pval, counter);

    mah_finalize_kernel<<<MAH_BLOCKS, 256, 0, stream>>>(
        T, src, tar, cs, ct, pval, bsum, counter, out);
}

// Round 5
// 35.258 us; speedup vs baseline: 1.8926x; 1.1756x over previous
//
#include <hip/hip_runtime.h>
#include <math.h>

#define N_PTS 12000
#define NT_CHUNKS 150
#define CHUNK 80             // N_TAR / NT_CHUNKS (exact)
#define SRC_PER_BLOCK 2048   // 256 threads * 8 src each
#define SRC_BLOCKS 6         // 6*2048 = 12288 >= 12000 (clamped tail)
#define MAH_BLOCKS 188       // ceil(12000/64) : 64 sources per block
#define RES_PER_WAVE 20      // CHUNK / 4 waves

// ---------------------------------------------------------------------------
// Kernel 1: brute-force NN partial min (VALUE ONLY). Unchanged from R4 —
// it is near its VALU floor (~4.25 VALU/pair).
// score(i,j) = |tar_j3|^2 - 2*dot3(tsrc_i, tar_j); argmin-equivalent to the
// reference d2. All score math is explicit fmaf so kernel 2 can recompute
// identical bits. Block (0,0) resets the completion counter for kernel 2.
// ---------------------------------------------------------------------------
__global__ __launch_bounds__(256) void nn_partial_kernel(
    const float* __restrict__ T,
    const float* __restrict__ src,
    const float* __restrict__ tar,
    float* __restrict__ pval,
    unsigned int* __restrict__ counter)
{
    __shared__ float4 lds[CHUNK];
    const int tid   = threadIdx.x;
    const int sblk  = blockIdx.x;
    const int chunk = blockIdx.y;
    const int jbase = chunk * CHUNK;

    if (sblk == 0 && chunk == 0 && tid == 0) atomicExch(counter, 0u);

    const float T00=T[0],  T01=T[1],  T02=T[2],  T03=T[3];
    const float T10=T[4],  T11=T[5],  T12=T[6],  T13=T[7];
    const float T20=T[8],  T21=T[9],  T22=T[10], T23=T[11];

    if (tid < CHUNK) {
        float4 t = ((const float4*)tar)[jbase + tid];
        float n3 = fmaf(t.x, t.x, fmaf(t.y, t.y, t.z * t.z));
        lds[tid] = make_float4(t.x, t.y, t.z, n3);
    }
    __syncthreads();

    float sx[8], sy[8], sz[8], mval[8];
    const int base = sblk * SRC_PER_BLOCK + tid;
    #pragma unroll
    for (int k = 0; k < 8; ++k) {
        int i = base + k * 256;
        if (i >= N_PTS) i = N_PTS - 1;          // clamp (write is guarded)
        float4 p = ((const float4*)src)[i];
        float tx = fmaf(T00, p.x, fmaf(T01, p.y, fmaf(T02, p.z, T03 * p.w)));
        float ty = fmaf(T10, p.x, fmaf(T11, p.y, fmaf(T12, p.z, T13 * p.w)));
        float tz = fmaf(T20, p.x, fmaf(T21, p.y, fmaf(T22, p.z, T23 * p.w)));
        sx[k] = -2.0f * tx;
        sy[k] = -2.0f * ty;
        sz[k] = -2.0f * tz;
        mval[k] = INFINITY;
    }

    #pragma unroll 4
    for (int j = 0; j < CHUNK; ++j) {
        const float4 t = lds[j];
        #pragma unroll
        for (int k = 0; k < 8; ++k) {
            float s = fmaf(sx[k], t.x, fmaf(sy[k], t.y, fmaf(sz[k], t.z, t.w)));
            mval[k] = fminf(mval[k], s);
        }
    }

    #pragma unroll
    for (int k = 0; k < 8; ++k) {
        int i = base + k * 256;
        if (i < N_PTS) pval[chunk * N_PTS + i] = mval[k];
    }
}

// ---------------------------------------------------------------------------
// Kernel 2: 64 sources per block (lane = source), 4 waves split the work.
// A: each wave reduces chunks {wv, wv+4, ...} (coalesced pval loads).
// B: LDS lexicographic (val, chunk) combine -> winning chunk (smallest chunk
//    on value ties = chunk holding the global first argmin).
// C: rescan of the 80-target chunk split 20/wave, bit-identical fmaf math,
//    (val, j) lexicographic combine -> reference first-argmin index.
// D: wave 0: covariance congruence + 3x3 adjugate inverse + Mahalanobis,
//    one lane per source; shuffle reduce -> bsum[block].
// E: last finished block does the fixed-order final reduce (deterministic).
// ---------------------------------------------------------------------------
__global__ __launch_bounds__(256) void mah_finalize_kernel(
    const float* __restrict__ T,
    const float* __restrict__ src,
    const float* __restrict__ tar,
    const float* __restrict__ cs,   // covs_src  [N][16]
    const float* __restrict__ ct,   // covs_tar  [N][16]
    const float* __restrict__ pval,
    float* __restrict__ bsum,
    unsigned int* __restrict__ counter,
    float* __restrict__ out)
{
    __shared__ float lds_v[4][64];
    __shared__ int   lds_i[4][64];

    const int lane = threadIdx.x & 63;
    const int wv   = threadIdx.x >> 6;
    const int i    = blockIdx.x * 64 + lane;
    const int ic   = (i < N_PTS) ? i : (N_PTS - 1);
    const float4* tar4 = (const float4*)tar;

    // --- Phase A: per-wave chunk-subset reduce (coalesced) ---
    float bv = INFINITY; int bc = 0;
    #pragma unroll 8
    for (int c = wv; c < NT_CHUNKS; c += 4) {
        float v = pval[c * N_PTS + ic];
        if (v < bv) { bv = v; bc = c; }
    }
    lds_v[wv][lane] = bv;
    lds_i[wv][lane] = bc;
    __syncthreads();

    // --- Phase B: lexicographic (val, chunk) min across waves ---
    float cv = lds_v[0][lane]; int cc = lds_i[0][lane];
    #pragma unroll
    for (int w = 1; w < 4; ++w) {
        float v = lds_v[w][lane]; int c = lds_i[w][lane];
        if (v < cv || (v == cv && c < cc)) { cv = v; cc = c; }
    }
    __syncthreads();

    // --- Phase C: rescan winning chunk, 20 targets per wave ---
    float Tm[4][4];
    #pragma unroll
    for (int a = 0; a < 16; ++a) ((float*)Tm)[a] = T[a];

    const float4 p = ((const float4*)src)[ic];
    const float tx = fmaf(Tm[0][0], p.x, fmaf(Tm[0][1], p.y, fmaf(Tm[0][2], p.z, Tm[0][3] * p.w)));
    const float ty = fmaf(Tm[1][0], p.x, fmaf(Tm[1][1], p.y, fmaf(Tm[1][2], p.z, Tm[1][3] * p.w)));
    const float tz = fmaf(Tm[2][0], p.x, fmaf(Tm[2][1], p.y, fmaf(Tm[2][2], p.z, Tm[2][3] * p.w)));
    const float sx = -2.0f * tx, sy = -2.0f * ty, sz = -2.0f * tz;

    const int jb = cc * CHUNK + wv * RES_PER_WAVE;
    float rv = INFINITY; int rj = 0;
    #pragma unroll 5
    for (int jj = 0; jj < RES_PER_WAVE; ++jj) {
        float4 t = tar4[jb + jj];
        float n3 = fmaf(t.x, t.x, fmaf(t.y, t.y, t.z * t.z));
        float s  = fmaf(sx, t.x, fmaf(sy, t.y, fmaf(sz, t.z, n3)));
        if (s < rv) { rv = s; rj = jb + jj; }
    }
    lds_v[wv][lane] = rv;
    lds_i[wv][lane] = rj;
    __syncthreads();

    // --- Phase D: wave 0 finishes per-source work ---
    if (wv == 0) {
        float fv = lds_v[0][lane]; int bidx = lds_i[0][lane];
        #pragma unroll
        for (int w = 1; w < 4; ++w) {
            float v = lds_v[w][lane]; int j = lds_i[w][lane];
            if (v < fv || (v == fv && j < bidx)) { fv = v; bidx = j; }
        }

        float C[4][4];
        #pragma unroll
        for (int a = 0; a < 16; ++a) ((float*)C)[a] = cs[ic * 16 + a];

        float B[4][3];
        #pragma unroll
        for (int j = 0; j < 4; ++j)
            #pragma unroll
            for (int c = 0; c < 3; ++c)
                B[j][c] = C[j][0]*Tm[c][0] + C[j][1]*Tm[c][1]
                        + C[j][2]*Tm[c][2] + C[j][3]*Tm[c][3];

        const float* ctb = ct + (size_t)bidx * 16;
        float M[3][3];
        #pragma unroll
        for (int r = 0; r < 3; ++r)
            #pragma unroll
            for (int c = 0; c < 3; ++c)
                M[r][c] = Tm[r][0]*B[0][c] + Tm[r][1]*B[1][c]
                        + Tm[r][2]*B[2][c] + Tm[r][3]*B[3][c]
                        + ctb[r * 4 + c];

        const float a_ = M[0][0], b_ = M[0][1], c_ = M[0][2];
        const float d_ = M[1][0], e_ = M[1][1], f_ = M[1][2];
        const float g_ = M[2][0], h_ = M[2][1], i_ = M[2][2];

        const float A0 = e_*i_ - f_*h_;
        const float A1 = f_*g_ - d_*i_;
        const float A2 = d_*h_ - e_*g_;
        const float det = a_*A0 + b_*A1 + c_*A2;
        const float rdet = 1.0f / det;

        float inv[3][3];
        inv[0][0] = A0 * rdet;
        inv[0][1] = (c_*h_ - b_*i_) * rdet;
        inv[0][2] = (b_*f_ - c_*e_) * rdet;
        inv[1][0] = A1 * rdet;
        inv[1][1] = (a_*i_ - c_*g_) * rdet;
        inv[1][2] = (c_*d_ - a_*f_) * rdet;
        inv[2][0] = A2 * rdet;
        inv[2][1] = (b_*g_ - a_*h_) * rdet;
        inv[2][2] = (a_*e_ - b_*d_) * rdet;

        // loss branch: pT = src @ T (columns of T)
        const float p0 = p.x*Tm[0][0] + p.y*Tm[1][0] + p.z*Tm[2][0] + p.w*Tm[3][0];
        const float p1 = p.x*Tm[0][1] + p.y*Tm[1][1] + p.z*Tm[2][1] + p.w*Tm[3][1];
        const float p2 = p.x*Tm[0][2] + p.y*Tm[1][2] + p.z*Tm[2][2] + p.w*Tm[3][2];

        const float4 tp = tar4[bidx];
        const float r0 = tp.x - p0;
        const float r1 = tp.y - p1;
        const float r2 = tp.z - p2;

        float mah = r0*(inv[0][0]*r0 + inv[0][1]*r1 + inv[0][2]*r2)
                  + r1*(inv[1][0]*r0 + inv[1][1]*r1 + inv[1][2]*r2)
                  + r2*(inv[2][0]*r0 + inv[2][1]*r1 + inv[2][2]*r2);
        if (i >= N_PTS) mah = 0.0f;

        // wave reduce (deterministic)
        #pragma unroll
        for (int off = 32; off > 0; off >>= 1)
            mah += __shfl_down(mah, off, 64);

        unsigned int old = 0u;
        if (lane == 0) {
            bsum[blockIdx.x] = mah;
            __threadfence();
            old = atomicAdd(counter, 1u);
        }
        old = __shfl(old, 0, 64);

        // --- Phase E: last block: fixed-order final reduce ---
        if (old == MAH_BLOCKS - 1) {
            __threadfence();   // acquire
            double acc = 0.0;
            for (int s = lane; s < MAH_BLOCKS; s += 64)
                acc += (double)atomicAdd(&bsum[s], 0.0f);   // coherent read
            #pragma unroll
            for (int off = 32; off > 0; off >>= 1)
                acc += __shfl_down(acc, off, 64);
            if (lane == 0)
                out[0] = (float)(acc / (double)N_PTS);
        }
    }
}

extern "C" void kernel_launch(void* const* d_in, const int* in_sizes, int n_in,
                              void* d_out, int out_size, void* d_ws, size_t ws_size,
                              hipStream_t stream) {
    const float* T   = (const float*)d_in[0];
    const float* src = (const float*)d_in[1];
    const float* tar = (const float*)d_in[2];
    const float* cs  = (const float*)d_in[3];
    const float* ct  = (const float*)d_in[4];
    float* out = (float*)d_out;

    char* ws = (char*)d_ws;
    unsigned int* counter = (unsigned int*)ws;             // 4 B
    float* bsum = (float*)(ws + 256);                      // 188 floats
    float* pval = (float*)(ws + 4096);                     // 150*12000*4 = 7.2 MB

    dim3 g1(SRC_BLOCKS, NT_CHUNKS);
    nn_partial_kernel<<<g1, 256, 0, stream>>>(T, src, tar, pval, counter);

    mah_finalize_kernel<<<MAH_BLOCKS, 256, 0, stream>>>(
        T, src, tar, cs, ct, pval, bsum, counter, out);
}